// Round 16
// baseline (6345.014 us; speedup 1.0000x reference)
//
#include <hip/hip_runtime.h>
#include <math.h>

#define NB 8
#define HID 512

typedef unsigned int uint4v __attribute__((ext_vector_type(4)));
typedef __attribute__((ext_vector_type(8))) short short8v;   // 8 bf16 (4 VGPRs)
typedef __attribute__((ext_vector_type(4))) float f32x4;     // MFMA acc

// ---------------------------------------------------------------------------
// helpers
// ---------------------------------------------------------------------------
__device__ __forceinline__ float sigf(float x) { return 1.0f / (1.0f + __expf(-x)); }
__device__ __forceinline__ float tanhf_(float x) {
    return 2.0f / (1.0f + __expf(-2.0f * x)) - 1.0f;
}
__device__ __forceinline__ unsigned short f2bf(float f) {  // RNE f32->bf16
    unsigned u = __float_as_uint(f);
    return (unsigned short)((u + 0x7FFFu + ((u >> 16) & 1u)) >> 16);
}

// ---------------------------------------------------------------------------
// 0) zero both tagged-h buffers (graph replays reuse ws). 16384 u64.
// ---------------------------------------------------------------------------
__global__ void init_ws_kernel(unsigned long long* h_bufs) {
    h_bufs[blockIdx.x * 256 + threadIdx.x] = 0ull;
}

// ---------------------------------------------------------------------------
// 0b) fp32 -> bf16 weight conversion (per launch; ~2.5MB, negligible)
// ---------------------------------------------------------------------------
__global__ void cvt_bf16_kernel(const float* __restrict__ src,
                                unsigned short* __restrict__ dst, int n4) {
    int i = blockIdx.x * 256 + threadIdx.x;
    if (i < n4) {
        float4 v = *(const float4*)(src + i * 4);
        unsigned lo = (unsigned)f2bf(v.x) | ((unsigned)f2bf(v.y) << 16);
        unsigned hi = (unsigned)f2bf(v.z) | ((unsigned)f2bf(v.w) << 16);
        *(uint2*)(dst + i * 4) = make_uint2(lo, hi);
    }
}

// ---------------------------------------------------------------------------
// 1) LayerNorm for one chunk — emits fp32 res + bf16 res (GEMM A operand)
// ---------------------------------------------------------------------------
__global__ void ln_kernel(const float* __restrict__ x, const float* __restrict__ gamma,
                          const float* __restrict__ beta, float* __restrict__ res,
                          unsigned short* __restrict__ res_bf,
                          int t0, int chsh) {
    int wid = threadIdx.x >> 6, lane = threadIdx.x & 63;
    int rl = blockIdx.x * 4 + wid;
    int b = rl >> chsh, i = rl & ((1 << chsh) - 1);
    const float* xr = x + (long long)(b * 4096 + t0 + i) * HID;
    float4 u0 = *(const float4*)(xr + lane * 4);
    float4 u1 = *(const float4*)(xr + 256 + lane * 4);
    float s = u0.x + u0.y + u0.z + u0.w + u1.x + u1.y + u1.z + u1.w;
#pragma unroll
    for (int m = 1; m < 64; m <<= 1) s += __shfl_xor(s, m, 64);
    float mu = s * (1.0f / 512.0f);
    float d[8] = {u0.x - mu, u0.y - mu, u0.z - mu, u0.w - mu,
                  u1.x - mu, u1.y - mu, u1.z - mu, u1.w - mu};
    float q = d[0]*d[0] + d[1]*d[1] + d[2]*d[2] + d[3]*d[3] +
              d[4]*d[4] + d[5]*d[5] + d[6]*d[6] + d[7]*d[7];
#pragma unroll
    for (int m = 1; m < 64; m <<= 1) q += __shfl_xor(q, m, 64);
    float rs = rsqrtf(q * (1.0f / 512.0f) + 1e-5f);
    float4 g0 = *(const float4*)(gamma + lane * 4);
    float4 g1 = *(const float4*)(gamma + 256 + lane * 4);
    float4 b0 = *(const float4*)(beta + lane * 4);
    float4 b1 = *(const float4*)(beta + 256 + lane * 4);
    float* rr = res + (long long)rl * HID;
    float4 o0, o1;
    o0.x = d[0] * rs * g0.x + b0.x; o0.y = d[1] * rs * g0.y + b0.y;
    o0.z = d[2] * rs * g0.z + b0.z; o0.w = d[3] * rs * g0.w + b0.w;
    o1.x = d[4] * rs * g1.x + b1.x; o1.y = d[5] * rs * g1.y + b1.y;
    o1.z = d[6] * rs * g1.z + b1.z; o1.w = d[7] * rs * g1.w + b1.w;
    *(float4*)(rr + lane * 4) = o0;
    *(float4*)(rr + 256 + lane * 4) = o1;
    unsigned short* rb = res_bf + (long long)rl * HID;
    *(uint2*)(rb + lane * 4) = make_uint2(
        (unsigned)f2bf(o0.x) | ((unsigned)f2bf(o0.y) << 16),
        (unsigned)f2bf(o0.z) | ((unsigned)f2bf(o0.w) << 16));
    *(uint2*)(rb + 256 + lane * 4) = make_uint2(
        (unsigned)f2bf(o1.x) | ((unsigned)f2bf(o1.y) << 16),
        (unsigned)f2bf(o1.z) | ((unsigned)f2bf(o1.w) << 16));
}

// ---------------------------------------------------------------------------
// 2) bf16 MFMA GEMM (verified round 15: absmax 0.031, MODE0+MODE1 correct)
// ---------------------------------------------------------------------------
template <int MODE>
__launch_bounds__(256, 2)
__global__ void gemm_mfma(const unsigned short* __restrict__ A,
                          const unsigned short* __restrict__ B,
                          const float* __restrict__ bias1, const float* __restrict__ bias2,
                          float* __restrict__ C, int N) {
    __shared__ unsigned short Al[128][72];
    __shared__ unsigned short Bl[128][72];
    int tid = threadIdx.x;
    int lane = tid & 63, wv = tid >> 6;
    int wr = wv >> 1, wc = wv & 1;
    int r0 = blockIdx.x * 128, j0 = blockIdx.y * 128;
    int srow = tid & 127, scol = (tid >> 7) * 32;

    f32x4 acc[4][4];
#pragma unroll
    for (int m = 0; m < 4; m++)
#pragma unroll
        for (int n = 0; n < 4; n++) acc[m][n] = (f32x4){0.f, 0.f, 0.f, 0.f};

    for (int kt = 0; kt < 512; kt += 64) {
        const unsigned short* ag = A + (long long)(r0 + srow) * 512 + kt + scol;
        const unsigned short* bg = B + (long long)(j0 + srow) * 512 + kt + scol;
        float4 av0 = ((const float4*)ag)[0], av1 = ((const float4*)ag)[1],
               av2 = ((const float4*)ag)[2], av3 = ((const float4*)ag)[3];
        float4 bv0 = ((const float4*)bg)[0], bv1 = ((const float4*)bg)[1],
               bv2 = ((const float4*)bg)[2], bv3 = ((const float4*)bg)[3];
        __syncthreads();
        float4* ad = (float4*)&Al[srow][scol];
        ad[0] = av0; ad[1] = av1; ad[2] = av2; ad[3] = av3;
        float4* bd = (float4*)&Bl[srow][scol];
        bd[0] = bv0; bd[1] = bv1; bd[2] = bv2; bd[3] = bv3;
        __syncthreads();
#pragma unroll
        for (int kk = 0; kk < 2; kk++) {
            int krow = kk * 32 + ((lane >> 4) << 3);
            short8v af[4], bf[4];
#pragma unroll
            for (int m = 0; m < 4; m++)
                af[m] = *(const short8v*)&Al[wr * 64 + m * 16 + (lane & 15)][krow];
#pragma unroll
            for (int n = 0; n < 4; n++)
                bf[n] = *(const short8v*)&Bl[wc * 64 + n * 16 + (lane & 15)][krow];
#pragma unroll
            for (int m = 0; m < 4; m++)
#pragma unroll
                for (int n = 0; n < 4; n++)
                    acc[m][n] = __builtin_amdgcn_mfma_f32_16x16x32_bf16(
                        af[m], bf[n], acc[m][n], 0, 0, 0);
        }
    }

    int cl = lane & 15, rl4 = (lane >> 4) << 2;
#pragma unroll
    for (int n = 0; n < 4; n++) {
        int j = j0 + wc * 64 + n * 16 + cl;
        float bb = (MODE == 0) ? (bias1[j] + bias2[j]) : bias1[j];
#pragma unroll
        for (int m = 0; m < 4; m++) {
#pragma unroll
            for (int reg = 0; reg < 4; reg++) {
                long long r = r0 + wr * 64 + m * 16 + rl4 + reg;
                float tv = acc[m][n][reg] + bb;
                if (MODE == 1) tv = tv * sigf(tv);
                C[r * (long long)N + j] = tv;
            }
        }
    }
}

// ---------------------------------------------------------------------------
// 3) LSTM scan — round-14/15 verified base (2.91ms/chunk) with ONE change:
//    3-deep nt poll pipeline (pa/pb/pc rotation, counted vmcnt(2)).
//    Model (calibrated r7->r9: detect = visibility + RT(1+1/k), RT~900cyc):
//    k=2->3 predicts -RT/6 ~ 62ns/step ~ 0.26ms total. nt request rate
//    1.5x of k=2 (~1TB/s chip-wide) — well under MALL service bw; r12's
//    congestion was sc1-flavored (TCC-processed), not applicable to nt.
//    In-order vmcnt FIFO: after issuing the 3rd load, vmcnt(2) completes
//    exactly the oldest (the register about to be checked); same-dest
//    completions are in-order; step-boundary leftovers are older and drain
//    in the first wait. pa/pb/pc PINNED by the end-of-kernel tying drain
//    (r9 register-lifetime rule).
//    LDS map (floats): [0,1024) h_s[2][512] | [1024,9216) epi_xp[2][64][4][16]
//    | [9216,11264) epi_g[2][64][16] | [11264,13312) epi_r[2][64][16]
// ---------------------------------------------------------------------------
__launch_bounds__(256, 1)
__global__ void scan_kernel(const float* __restrict__ W_hh,   // [2048][512]
                            const float* __restrict__ xp,     // [8*CH][2048]
                            const float* __restrict__ resv,   // [8*CH][512]
                            const float* __restrict__ gatev,  // [8*CH][512]
                            float* __restrict__ out,          // d_out
                            unsigned long long* __restrict__ h_fast, // [2][8][512]
                            unsigned long long* __restrict__ h_safe, // [2][8][512]
                            float* __restrict__ c_buf,        // [8][512]
                            int t0, int chsh) {
    const int CH = 1 << chsh;
    int b = blockIdx.x & 7, w = blockIdx.x >> 3;
    int tid = threadIdx.x;
    int kg = tid & 15, rq = tid >> 4;
    int slot = w * 16 + rq;

    __shared__ __align__(16) float lds[13312];

    const int ep_s = tid >> 2;
    const int ep_g = tid & 3;
    const int gr_s = tid & 63;

    float wreg[4][32];
#pragma unroll
    for (int g = 0; g < 4; g++) {
        const float* wr = W_hh + (long long)((g << 9) + slot) * 512 + (kg << 5);
#pragma unroll
        for (int q = 0; q < 8; q++) {
            float4 u = *(const float4*)(wr + q * 4);
            wreg[g][q * 4 + 0] = u.x; wreg[g][q * 4 + 1] = u.y;
            wreg[g][q * 4 + 2] = u.z; wreg[g][q * 4 + 3] = u.w;
        }
    }

    float c_reg = 0.0f;
    if (t0 > 0 && kg == 0) c_reg = c_buf[(b << 9) + slot];

    int mode = 0;                        // 0=fast(nt/MALL) 1=safe(agent) 2=dead
    const int pr0 = 2 * tid;
    const int n_w  = tid >> 1;
    const int pg_w = (n_w & ~7) | ((n_w ^ (n_w >> 3)) & 7);
    const int fi_w = (pg_w << 2) | (pr0 & 3);

    uint4v pa = {0, 0, 0, 0}, pb = {0, 0, 0, 0}, pc = {0, 0, 0, 0};  // 3-deep
                                                   // poll regs — PINNED
    float4 pfx0 = {0,0,0,0}, pfx1 = {0,0,0,0}, pfx2 = {0,0,0,0}, pfx3 = {0,0,0,0};
    float4 pfg0 = {0,0,0,0}, pfg1 = {0,0,0,0}, pfg2 = {0,0,0,0}, pfg3 = {0,0,0,0};

    {
        int row = (b << chsh) + ((ep_s < CH) ? ep_s : CH - 1);
        const float* xr = xp + (long long)row * 2048 + (ep_g << 9) + (w << 4);
        pfx0 = *(const float4*)(xr + 0);  pfx1 = *(const float4*)(xr + 4);
        pfx2 = *(const float4*)(xr + 8);  pfx3 = *(const float4*)(xr + 12);
        if (tid < 128) {
            int row2 = (b << chsh) + gr_s;
            const float* gr = (tid < 64 ? gatev : resv) + (long long)row2 * 512 + (w << 4);
            pfg0 = *(const float4*)(gr + 0);  pfg1 = *(const float4*)(gr + 4);
            pfg2 = *(const float4*)(gr + 8);  pfg3 = *(const float4*)(gr + 12);
        }
        asm volatile("s_waitcnt vmcnt(0)" ::: "memory");
        float* xd = lds + 1024 + (ep_s << 6) + (ep_g << 4);
        *(float4*)(xd + 0) = pfx0;  *(float4*)(xd + 4) = pfx1;
        *(float4*)(xd + 8) = pfx2;  *(float4*)(xd + 12) = pfx3;
        if (tid < 128) {
            float* gd = lds + (tid < 64 ? 9216 : 11264) + (gr_s << 4);
            *(float4*)(gd + 0) = pfg0;  *(float4*)(gd + 4) = pfg1;
            *(float4*)(gd + 8) = pfg2;  *(float4*)(gd + 12) = pfg3;
        }
    }

    for (int i = 0; i < CH; i++) {
        int t = t0 + i;
        int es = i & 63;
        int e = (i >> 6) & 1;
        int p = t & 1;

        float h0 = 0.0f, h1 = 0.0f;
        if (t > 0) {
            const int par = (t - 1) & 1;
            const unsigned exp_tag = (unsigned)t;
            bool got = false;
            if (mode == 0) {
                const unsigned long long* fb = h_fast + par * 4096 + (b << 9) + pr0;
                int tries = 0;
                asm volatile("global_load_dwordx4 %0, %1, off nt"
                             : "=v"(pa) : "v"(fb) : "memory");
                asm volatile("global_load_dwordx4 %0, %1, off nt"
                             : "=v"(pb) : "v"(fb) : "memory");
                while (true) {
                    asm volatile("global_load_dwordx4 %0, %1, off nt"
                                 : "=v"(pc) : "v"(fb) : "memory");
                    asm volatile("s_waitcnt vmcnt(2)" : "+v"(pa) :: "memory");
                    if (pa[1] == exp_tag && pa[3] == exp_tag) {
                        h0 = __uint_as_float(pa[0]); h1 = __uint_as_float(pa[2]);
                        got = true; break;
                    }
                    asm volatile("global_load_dwordx4 %0, %1, off nt"
                                 : "=v"(pa) : "v"(fb) : "memory");
                    asm volatile("s_waitcnt vmcnt(2)" : "+v"(pb) :: "memory");
                    if (pb[1] == exp_tag && pb[3] == exp_tag) {
                        h0 = __uint_as_float(pb[0]); h1 = __uint_as_float(pb[2]);
                        got = true; break;
                    }
                    asm volatile("global_load_dwordx4 %0, %1, off nt"
                                 : "=v"(pb) : "v"(fb) : "memory");
                    asm volatile("s_waitcnt vmcnt(2)" : "+v"(pc) :: "memory");
                    if (pc[1] == exp_tag && pc[3] == exp_tag) {
                        h0 = __uint_as_float(pc[0]); h1 = __uint_as_float(pc[2]);
                        got = true; break;
                    }
                    if (++tries > 341) { mode = 1; break; }   // ~1024 loads total
                }
            }
            if (!got) {
                const unsigned long long* sb = h_safe + par * 4096 + (b << 9);
                unsigned long long v0 = 0, v1 = 0;
                if (mode == 1) {
                    bool g0 = false, g1 = false;
                    int tr = 0;
                    while (true) {
                        if (!g0) {
                            v0 = __hip_atomic_load(sb + pr0, __ATOMIC_RELAXED,
                                                   __HIP_MEMORY_SCOPE_AGENT);
                            g0 = ((unsigned)(v0 >> 32) == exp_tag);
                        }
                        if (!g1) {
                            v1 = __hip_atomic_load(sb + pr0 + 1, __ATOMIC_RELAXED,
                                                   __HIP_MEMORY_SCOPE_AGENT);
                            g1 = ((unsigned)(v1 >> 32) == exp_tag);
                        }
                        if (g0 && g1) break;
                        if (++tr > (1 << 15)) { mode = 2; break; }
                    }
                } else {
                    v0 = __hip_atomic_load(sb + pr0, __ATOMIC_RELAXED,
                                           __HIP_MEMORY_SCOPE_AGENT);
                    v1 = __hip_atomic_load(sb + pr0 + 1, __ATOMIC_RELAXED,
                                           __HIP_MEMORY_SCOPE_AGENT);
                }
                h0 = __uint_as_float((unsigned)v0);
                h1 = __uint_as_float((unsigned)v1);
            }
            *(float2*)&lds[(p << 9) + fi_w] = make_float2(h0, h1);
        }

        if (es == 0) {
            int ib = i + 64;
            int sx = ib + ep_s; if (sx > CH - 1) sx = CH - 1;
            const float* xr = xp + (long long)((b << chsh) + sx) * 2048 + (ep_g << 9) + (w << 4);
            pfx0 = *(const float4*)(xr + 0);  pfx1 = *(const float4*)(xr + 4);
            pfx2 = *(const float4*)(xr + 8);  pfx3 = *(const float4*)(xr + 12);
            if (tid < 128) {
                int sy = ib + gr_s; if (sy > CH - 1) sy = CH - 1;
                const float* gr = (tid < 64 ? gatev : resv) + (long long)((b << chsh) + sy) * 512 + (w << 4);
                pfg0 = *(const float4*)(gr + 0);  pfg1 = *(const float4*)(gr + 4);
                pfg2 = *(const float4*)(gr + 8);  pfg3 = *(const float4*)(gr + 12);
            }
        }
        if (es == 1) {
            asm volatile("s_waitcnt vmcnt(0)" ::: "memory");
            int eo = e ^ 1;
            float* xd = lds + 1024 + (eo << 12) + (ep_s << 6) + (ep_g << 4);
            *(float4*)(xd + 0) = pfx0;  *(float4*)(xd + 4) = pfx1;
            *(float4*)(xd + 8) = pfx2;  *(float4*)(xd + 12) = pfx3;
            if (tid < 128) {
                float* gd = lds + (tid < 64 ? 9216 : 11264) + (eo << 10) + (gr_s << 4);
                *(float4*)(gd + 0) = pfg0;  *(float4*)(gd + 4) = pfg1;
                *(float4*)(gd + 8) = pfg2;  *(float4*)(gd + 12) = pfg3;
            }
        }

        asm volatile("s_waitcnt lgkmcnt(0)" ::: "memory");
        __builtin_amdgcn_s_barrier();
        asm volatile("" ::: "memory");

        float acc0 = 0, acc1 = 0, acc2 = 0, acc3 = 0;
        if (t > 0) {
            float hv[32];
#pragma unroll
            for (int q = 0; q < 8; q++) {
                int pg = (kg << 3) + (q ^ (kg & 7));
                float4 u = *(const float4*)&lds[(p << 9) + (pg << 2)];
                hv[q * 4 + 0] = u.x; hv[q * 4 + 1] = u.y;
                hv[q * 4 + 2] = u.z; hv[q * 4 + 3] = u.w;
            }
#pragma unroll
            for (int j = 0; j < 32; j++) {
                acc0 += hv[j] * wreg[0][j];
                acc1 += hv[j] * wreg[1][j];
                acc2 += hv[j] * wreg[2][j];
                acc3 += hv[j] * wreg[3][j];
            }
            acc0 += __shfl_xor(acc0, 1, 64); acc0 += __shfl_xor(acc0, 2, 64);
            acc0 += __shfl_xor(acc0, 4, 64); acc0 += __shfl_xor(acc0, 8, 64);
            acc1 += __shfl_xor(acc1, 1, 64); acc1 += __shfl_xor(acc1, 2, 64);
            acc1 += __shfl_xor(acc1, 4, 64); acc1 += __shfl_xor(acc1, 8, 64);
            acc2 += __shfl_xor(acc2, 1, 64); acc2 += __shfl_xor(acc2, 2, 64);
            acc2 += __shfl_xor(acc2, 4, 64); acc2 += __shfl_xor(acc2, 8, 64);
            acc3 += __shfl_xor(acc3, 1, 64); acc3 += __shfl_xor(acc3, 2, 64);
            acc3 += __shfl_xor(acc3, 4, 64); acc3 += __shfl_xor(acc3, 8, 64);
        }

        if (kg == 0) {
            const float* eb = lds + 1024 + (e << 12) + (es << 6);
            float xpv0 = eb[rq];
            float xpv1 = eb[16 + rq];
            float xpv2 = eb[32 + rq];
            float xpv3 = eb[48 + rq];
            float gv = lds[9216 + (e << 10) + (es << 4) + rq];
            float rv = lds[11264 + (e << 10) + (es << 4) + rq];
            float iv = sigf(acc0 + xpv0);
            float fv = sigf(acc1 + xpv1);
            float gt = tanhf_(acc2 + xpv2);
            float ov = sigf(acc3 + xpv3);
            c_reg = fv * c_reg + iv * gt;
            float h = ov * tanhf_(c_reg);
            unsigned long long pkt =
                ((unsigned long long)(unsigned)(t + 1) << 32) |
                (unsigned long long)__float_as_uint(h);
            __hip_atomic_store(h_safe + p * 4096 + (b << 9) + slot, pkt,
                               __ATOMIC_RELAXED, __HIP_MEMORY_SCOPE_AGENT);
            unsigned long long* fp = h_fast + p * 4096 + (b << 9) + slot;
            asm volatile("global_store_dwordx2 %0, %1, off sc0"
                         :: "v"(fp), "v"(pkt) : "memory");
            out[(long long)((b << 12) + t) * 512 + slot] = h * gv + rv;
            if (t == 4095) {
                out[16777216 + (b << 9) + slot] = h;            // hT
                out[16777216 + 4096 + (b << 9) + slot] = c_reg; // cT
            }
            if (i == CH - 1) c_buf[(b << 9) + slot] = c_reg;
        }
    }
    // END-OF-KERNEL TYING DRAIN: pa/pb/pc as INPUTS -> live (pinned) for the
    // whole kernel; drains leftover in-flight poll loads before reuse/exit.
    asm volatile("s_waitcnt vmcnt(0)" :: "v"(pa), "v"(pb), "v"(pc) : "memory");
}

// ---------------------------------------------------------------------------
// launch: chunk T so the workspace fits ws_size.
// per-CH bytes: 106496*CH; persistent ~2.8MB
// ---------------------------------------------------------------------------
extern "C" void kernel_launch(void* const* d_in, const int* in_sizes, int n_in,
                              void* d_out, int out_size, void* d_ws, size_t ws_size,
                              hipStream_t stream) {
    const float* x     = (const float*)d_in[0];
    const float* W_ih  = (const float*)d_in[1];
    const float* W_hh  = (const float*)d_in[2];
    const float* b_ih  = (const float*)d_in[3];
    const float* b_hh  = (const float*)d_in[4];
    const float* gamma = (const float*)d_in[5];
    const float* beta  = (const float*)d_in[6];
    const float* W_lin = (const float*)d_in[7];
    const float* b_lin = (const float*)d_in[8];
    float* out = (float*)d_out;

    const size_t small_bytes = 16384ull * 8 + 4096ull * 4 +
                               (2048ull * 512 + 512ull * 512) * 2;
    int CH = 256;
    for (int cand = 4096; cand >= 256; cand >>= 1) {
        if ((size_t)106496 * cand + small_bytes <= ws_size) { CH = cand; break; }
    }
    int chsh = 31 - __builtin_clz(CH);

    float* ws      = (float*)d_ws;
    float* res_ch  = ws;
    float* gate_ch = res_ch + (size_t)8 * CH * 512;
    float* xp_ch   = gate_ch + (size_t)8 * CH * 512;
    unsigned short* res_bf = (unsigned short*)(xp_ch + (size_t)8 * CH * 2048);
    unsigned long long* h_fast = (unsigned long long*)(res_bf + (size_t)8 * CH * 512);
    unsigned long long* h_safe = h_fast + 8192;
    float* c_buf   = (float*)(h_safe + 8192);
    unsigned short* wbf_ih  = (unsigned short*)(c_buf + 4096);
    unsigned short* wbf_lin = wbf_ih + 2048 * 512;

    init_ws_kernel<<<64, 256, 0, stream>>>(h_fast);  // zeroes h_fast + h_safe
    cvt_bf16_kernel<<<1024, 256, 0, stream>>>(W_ih, wbf_ih, 2048 * 512 / 4);
    cvt_bf16_kernel<<<256, 256, 0, stream>>>(W_lin, wbf_lin, 512 * 512 / 4);

    int nchunks = 4096 / CH;
    for (int c = 0; c < nchunks; c++) {
        int t0 = c * CH;
        ln_kernel<<<8 * CH / 4, 256, 0, stream>>>(x, gamma, beta, res_ch, res_bf,
                                                  t0, chsh);
        gemm_mfma<0><<<dim3(8 * CH / 128, 16), 256, 0, stream>>>(
            res_bf, wbf_ih, b_ih, b_hh, xp_ch, 2048);
        gemm_mfma<1><<<dim3(8 * CH / 128, 4), 256, 0, stream>>>(
            res_bf, wbf_lin, b_lin, b_lin, gate_ch, 512);
        scan_kernel<<<256, 256, 0, stream>>>(W_hh, xp_ch, res_ch, gate_ch, out,
                                             h_fast, h_safe, c_buf, t0, chsh);
    }
}

// Round 17
// 5915.074 us; speedup vs baseline: 1.0727x; 1.0727x over previous
//
#include <hip/hip_runtime.h>
#include <math.h>

#define NB 8
#define HID 512

typedef unsigned int uint4v __attribute__((ext_vector_type(4)));
typedef __attribute__((ext_vector_type(8))) short short8v;   // 8 bf16 (4 VGPRs)
typedef __attribute__((ext_vector_type(4))) float f32x4;     // MFMA acc

// ---------------------------------------------------------------------------
// helpers
// ---------------------------------------------------------------------------
__device__ __forceinline__ float sigf(float x) { return 1.0f / (1.0f + __expf(-x)); }
__device__ __forceinline__ float tanhf_(float x) {
    return 2.0f / (1.0f + __expf(-2.0f * x)) - 1.0f;
}
__device__ __forceinline__ unsigned short f2bf(float f) {  // RNE f32->bf16
    unsigned u = __float_as_uint(f);
    return (unsigned short)((u + 0x7FFFu + ((u >> 16) & 1u)) >> 16);
}

// ---------------------------------------------------------------------------
// 0) zero both tagged-h buffers (graph replays reuse ws). 16384 u64.
// ---------------------------------------------------------------------------
__global__ void init_ws_kernel(unsigned long long* h_bufs) {
    h_bufs[blockIdx.x * 256 + threadIdx.x] = 0ull;
}

// ---------------------------------------------------------------------------
// 0b) fp32 -> bf16 weight conversion (per launch; ~2.5MB, negligible)
// ---------------------------------------------------------------------------
__global__ void cvt_bf16_kernel(const float* __restrict__ src,
                                unsigned short* __restrict__ dst, int n4) {
    int i = blockIdx.x * 256 + threadIdx.x;
    if (i < n4) {
        float4 v = *(const float4*)(src + i * 4);
        unsigned lo = (unsigned)f2bf(v.x) | ((unsigned)f2bf(v.y) << 16);
        unsigned hi = (unsigned)f2bf(v.z) | ((unsigned)f2bf(v.w) << 16);
        *(uint2*)(dst + i * 4) = make_uint2(lo, hi);
    }
}

// ---------------------------------------------------------------------------
// 1) LayerNorm for one chunk — emits fp32 res + bf16 res (GEMM A operand)
// ---------------------------------------------------------------------------
__global__ void ln_kernel(const float* __restrict__ x, const float* __restrict__ gamma,
                          const float* __restrict__ beta, float* __restrict__ res,
                          unsigned short* __restrict__ res_bf,
                          int t0, int chsh) {
    int wid = threadIdx.x >> 6, lane = threadIdx.x & 63;
    int rl = blockIdx.x * 4 + wid;
    int b = rl >> chsh, i = rl & ((1 << chsh) - 1);
    const float* xr = x + (long long)(b * 4096 + t0 + i) * HID;
    float4 u0 = *(const float4*)(xr + lane * 4);
    float4 u1 = *(const float4*)(xr + 256 + lane * 4);
    float s = u0.x + u0.y + u0.z + u0.w + u1.x + u1.y + u1.z + u1.w;
#pragma unroll
    for (int m = 1; m < 64; m <<= 1) s += __shfl_xor(s, m, 64);
    float mu = s * (1.0f / 512.0f);
    float d[8] = {u0.x - mu, u0.y - mu, u0.z - mu, u0.w - mu,
                  u1.x - mu, u1.y - mu, u1.z - mu, u1.w - mu};
    float q = d[0]*d[0] + d[1]*d[1] + d[2]*d[2] + d[3]*d[3] +
              d[4]*d[4] + d[5]*d[5] + d[6]*d[6] + d[7]*d[7];
#pragma unroll
    for (int m = 1; m < 64; m <<= 1) q += __shfl_xor(q, m, 64);
    float rs = rsqrtf(q * (1.0f / 512.0f) + 1e-5f);
    float4 g0 = *(const float4*)(gamma + lane * 4);
    float4 g1 = *(const float4*)(gamma + 256 + lane * 4);
    float4 b0 = *(const float4*)(beta + lane * 4);
    float4 b1 = *(const float4*)(beta + 256 + lane * 4);
    float* rr = res + (long long)rl * HID;
    float4 o0, o1;
    o0.x = d[0] * rs * g0.x + b0.x; o0.y = d[1] * rs * g0.y + b0.y;
    o0.z = d[2] * rs * g0.z + b0.z; o0.w = d[3] * rs * g0.w + b0.w;
    o1.x = d[4] * rs * g1.x + b1.x; o1.y = d[5] * rs * g1.y + b1.y;
    o1.z = d[6] * rs * g1.z + b1.z; o1.w = d[7] * rs * g1.w + b1.w;
    *(float4*)(rr + lane * 4) = o0;
    *(float4*)(rr + 256 + lane * 4) = o1;
    unsigned short* rb = res_bf + (long long)rl * HID;
    *(uint2*)(rb + lane * 4) = make_uint2(
        (unsigned)f2bf(o0.x) | ((unsigned)f2bf(o0.y) << 16),
        (unsigned)f2bf(o0.z) | ((unsigned)f2bf(o0.w) << 16));
    *(uint2*)(rb + 256 + lane * 4) = make_uint2(
        (unsigned)f2bf(o1.x) | ((unsigned)f2bf(o1.y) << 16),
        (unsigned)f2bf(o1.z) | ((unsigned)f2bf(o1.w) << 16));
}

// ---------------------------------------------------------------------------
// 2) bf16 MFMA GEMM (verified round 15: absmax 0.031, MODE0+MODE1 correct)
// ---------------------------------------------------------------------------
template <int MODE>
__launch_bounds__(256, 2)
__global__ void gemm_mfma(const unsigned short* __restrict__ A,
                          const unsigned short* __restrict__ B,
                          const float* __restrict__ bias1, const float* __restrict__ bias2,
                          float* __restrict__ C, int N) {
    __shared__ unsigned short Al[128][72];
    __shared__ unsigned short Bl[128][72];
    int tid = threadIdx.x;
    int lane = tid & 63, wv = tid >> 6;
    int wr = wv >> 1, wc = wv & 1;
    int r0 = blockIdx.x * 128, j0 = blockIdx.y * 128;
    int srow = tid & 127, scol = (tid >> 7) * 32;

    f32x4 acc[4][4];
#pragma unroll
    for (int m = 0; m < 4; m++)
#pragma unroll
        for (int n = 0; n < 4; n++) acc[m][n] = (f32x4){0.f, 0.f, 0.f, 0.f};

    for (int kt = 0; kt < 512; kt += 64) {
        const unsigned short* ag = A + (long long)(r0 + srow) * 512 + kt + scol;
        const unsigned short* bg = B + (long long)(j0 + srow) * 512 + kt + scol;
        float4 av0 = ((const float4*)ag)[0], av1 = ((const float4*)ag)[1],
               av2 = ((const float4*)ag)[2], av3 = ((const float4*)ag)[3];
        float4 bv0 = ((const float4*)bg)[0], bv1 = ((const float4*)bg)[1],
               bv2 = ((const float4*)bg)[2], bv3 = ((const float4*)bg)[3];
        __syncthreads();
        float4* ad = (float4*)&Al[srow][scol];
        ad[0] = av0; ad[1] = av1; ad[2] = av2; ad[3] = av3;
        float4* bd = (float4*)&Bl[srow][scol];
        bd[0] = bv0; bd[1] = bv1; bd[2] = bv2; bd[3] = bv3;
        __syncthreads();
#pragma unroll
        for (int kk = 0; kk < 2; kk++) {
            int krow = kk * 32 + ((lane >> 4) << 3);
            short8v af[4], bf[4];
#pragma unroll
            for (int m = 0; m < 4; m++)
                af[m] = *(const short8v*)&Al[wr * 64 + m * 16 + (lane & 15)][krow];
#pragma unroll
            for (int n = 0; n < 4; n++)
                bf[n] = *(const short8v*)&Bl[wc * 64 + n * 16 + (lane & 15)][krow];
#pragma unroll
            for (int m = 0; m < 4; m++)
#pragma unroll
                for (int n = 0; n < 4; n++)
                    acc[m][n] = __builtin_amdgcn_mfma_f32_16x16x32_bf16(
                        af[m], bf[n], acc[m][n], 0, 0, 0);
        }
    }

    int cl = lane & 15, rl4 = (lane >> 4) << 2;
#pragma unroll
    for (int n = 0; n < 4; n++) {
        int j = j0 + wc * 64 + n * 16 + cl;
        float bb = (MODE == 0) ? (bias1[j] + bias2[j]) : bias1[j];
#pragma unroll
        for (int m = 0; m < 4; m++) {
#pragma unroll
            for (int reg = 0; reg < 4; reg++) {
                long long r = r0 + wr * 64 + m * 16 + rl4 + reg;
                float tv = acc[m][n][reg] + bb;
                if (MODE == 1) tv = tv * sigf(tv);
                C[r * (long long)N + j] = tv;
            }
        }
    }
}

// ---------------------------------------------------------------------------
// 3) LSTM scan — round-15 verified optimum, restored byte-identical.
//    Poll-depth sweep complete: k=1 -> 3.27, k=2 -> 2.91 (THIS), k=3 -> 3.11
//    ms/chunk. k=2 is the measured optimum: deeper pipelines lose to MALL
//    request-rate cost + VGPR pressure; shallower loses RT/2 of detect.
//    Protocol: tagged packets (tag t+1 | f32 h), parity double buffer,
//    dual publish (safe agent-atomic first, fast sc0 store second),
//    2-deep nt ping-pong poll with counted vmcnt(1), pa/pb PINNED by
//    end-of-kernel tying drain; epi operands block-prefetched 64 steps into
//    dbuf LDS; raw s_barrier with lgkmcnt(0) only.
//    LDS map (floats): [0,1024) h_s[2][512] | [1024,9216) epi_xp[2][64][4][16]
//    | [9216,11264) epi_g[2][64][16] | [11264,13312) epi_r[2][64][16]
// ---------------------------------------------------------------------------
__launch_bounds__(256, 1)
__global__ void scan_kernel(const float* __restrict__ W_hh,   // [2048][512]
                            const float* __restrict__ xp,     // [8*CH][2048]
                            const float* __restrict__ resv,   // [8*CH][512]
                            const float* __restrict__ gatev,  // [8*CH][512]
                            float* __restrict__ out,          // d_out
                            unsigned long long* __restrict__ h_fast, // [2][8][512]
                            unsigned long long* __restrict__ h_safe, // [2][8][512]
                            float* __restrict__ c_buf,        // [8][512]
                            int t0, int chsh) {
    const int CH = 1 << chsh;
    int b = blockIdx.x & 7, w = blockIdx.x >> 3;
    int tid = threadIdx.x;
    int kg = tid & 15, rq = tid >> 4;
    int slot = w * 16 + rq;

    __shared__ __align__(16) float lds[13312];

    const int ep_s = tid >> 2;
    const int ep_g = tid & 3;
    const int gr_s = tid & 63;

    float wreg[4][32];
#pragma unroll
    for (int g = 0; g < 4; g++) {
        const float* wr = W_hh + (long long)((g << 9) + slot) * 512 + (kg << 5);
#pragma unroll
        for (int q = 0; q < 8; q++) {
            float4 u = *(const float4*)(wr + q * 4);
            wreg[g][q * 4 + 0] = u.x; wreg[g][q * 4 + 1] = u.y;
            wreg[g][q * 4 + 2] = u.z; wreg[g][q * 4 + 3] = u.w;
        }
    }

    float c_reg = 0.0f;
    if (t0 > 0 && kg == 0) c_reg = c_buf[(b << 9) + slot];

    int mode = 0;                        // 0=fast(nt/MALL) 1=safe(agent) 2=dead
    const int pr0 = 2 * tid;
    const int n_w  = tid >> 1;
    const int pg_w = (n_w & ~7) | ((n_w ^ (n_w >> 3)) & 7);
    const int fi_w = (pg_w << 2) | (pr0 & 3);

    uint4v pa = {0, 0, 0, 0}, pb = {0, 0, 0, 0};
    float4 pfx0 = {0,0,0,0}, pfx1 = {0,0,0,0}, pfx2 = {0,0,0,0}, pfx3 = {0,0,0,0};
    float4 pfg0 = {0,0,0,0}, pfg1 = {0,0,0,0}, pfg2 = {0,0,0,0}, pfg3 = {0,0,0,0};

    {
        int row = (b << chsh) + ((ep_s < CH) ? ep_s : CH - 1);
        const float* xr = xp + (long long)row * 2048 + (ep_g << 9) + (w << 4);
        pfx0 = *(const float4*)(xr + 0);  pfx1 = *(const float4*)(xr + 4);
        pfx2 = *(const float4*)(xr + 8);  pfx3 = *(const float4*)(xr + 12);
        if (tid < 128) {
            int row2 = (b << chsh) + gr_s;
            const float* gr = (tid < 64 ? gatev : resv) + (long long)row2 * 512 + (w << 4);
            pfg0 = *(const float4*)(gr + 0);  pfg1 = *(const float4*)(gr + 4);
            pfg2 = *(const float4*)(gr + 8);  pfg3 = *(const float4*)(gr + 12);
        }
        asm volatile("s_waitcnt vmcnt(0)" ::: "memory");
        float* xd = lds + 1024 + (ep_s << 6) + (ep_g << 4);
        *(float4*)(xd + 0) = pfx0;  *(float4*)(xd + 4) = pfx1;
        *(float4*)(xd + 8) = pfx2;  *(float4*)(xd + 12) = pfx3;
        if (tid < 128) {
            float* gd = lds + (tid < 64 ? 9216 : 11264) + (gr_s << 4);
            *(float4*)(gd + 0) = pfg0;  *(float4*)(gd + 4) = pfg1;
            *(float4*)(gd + 8) = pfg2;  *(float4*)(gd + 12) = pfg3;
        }
    }

    for (int i = 0; i < CH; i++) {
        int t = t0 + i;
        int es = i & 63;
        int e = (i >> 6) & 1;
        int p = t & 1;

        float h0 = 0.0f, h1 = 0.0f;
        if (t > 0) {
            const int par = (t - 1) & 1;
            const unsigned exp_tag = (unsigned)t;
            bool got = false;
            if (mode == 0) {
                const unsigned long long* fb = h_fast + par * 4096 + (b << 9) + pr0;
                int tries = 0;
                asm volatile("global_load_dwordx4 %0, %1, off nt"
                             : "=v"(pa) : "v"(fb) : "memory");
                while (true) {
                    asm volatile("global_load_dwordx4 %0, %1, off nt"
                                 : "=v"(pb) : "v"(fb) : "memory");
                    asm volatile("s_waitcnt vmcnt(1)" : "+v"(pa) :: "memory");
                    if (pa[1] == exp_tag && pa[3] == exp_tag) {
                        h0 = __uint_as_float(pa[0]); h1 = __uint_as_float(pa[2]);
                        got = true; break;
                    }
                    asm volatile("global_load_dwordx4 %0, %1, off nt"
                                 : "=v"(pa) : "v"(fb) : "memory");
                    asm volatile("s_waitcnt vmcnt(1)" : "+v"(pb) :: "memory");
                    if (pb[1] == exp_tag && pb[3] == exp_tag) {
                        h0 = __uint_as_float(pb[0]); h1 = __uint_as_float(pb[2]);
                        got = true; break;
                    }
                    if (++tries > 512) { mode = 1; break; }
                }
            }
            if (!got) {
                const unsigned long long* sb = h_safe + par * 4096 + (b << 9);
                unsigned long long v0 = 0, v1 = 0;
                if (mode == 1) {
                    bool g0 = false, g1 = false;
                    int tr = 0;
                    while (true) {
                        if (!g0) {
                            v0 = __hip_atomic_load(sb + pr0, __ATOMIC_RELAXED,
                                                   __HIP_MEMORY_SCOPE_AGENT);
                            g0 = ((unsigned)(v0 >> 32) == exp_tag);
                        }
                        if (!g1) {
                            v1 = __hip_atomic_load(sb + pr0 + 1, __ATOMIC_RELAXED,
                                                   __HIP_MEMORY_SCOPE_AGENT);
                            g1 = ((unsigned)(v1 >> 32) == exp_tag);
                        }
                        if (g0 && g1) break;
                        if (++tr > (1 << 15)) { mode = 2; break; }
                    }
                } else {
                    v0 = __hip_atomic_load(sb + pr0, __ATOMIC_RELAXED,
                                           __HIP_MEMORY_SCOPE_AGENT);
                    v1 = __hip_atomic_load(sb + pr0 + 1, __ATOMIC_RELAXED,
                                           __HIP_MEMORY_SCOPE_AGENT);
                }
                h0 = __uint_as_float((unsigned)v0);
                h1 = __uint_as_float((unsigned)v1);
            }
            *(float2*)&lds[(p << 9) + fi_w] = make_float2(h0, h1);
        }

        if (es == 0) {
            int ib = i + 64;
            int sx = ib + ep_s; if (sx > CH - 1) sx = CH - 1;
            const float* xr = xp + (long long)((b << chsh) + sx) * 2048 + (ep_g << 9) + (w << 4);
            pfx0 = *(const float4*)(xr + 0);  pfx1 = *(const float4*)(xr + 4);
            pfx2 = *(const float4*)(xr + 8);  pfx3 = *(const float4*)(xr + 12);
            if (tid < 128) {
                int sy = ib + gr_s; if (sy > CH - 1) sy = CH - 1;
                const float* gr = (tid < 64 ? gatev : resv) + (long long)((b << chsh) + sy) * 512 + (w << 4);
                pfg0 = *(const float4*)(gr + 0);  pfg1 = *(const float4*)(gr + 4);
                pfg2 = *(const float4*)(gr + 8);  pfg3 = *(const float4*)(gr + 12);
            }
        }
        if (es == 1) {
            asm volatile("s_waitcnt vmcnt(0)" ::: "memory");
            int eo = e ^ 1;
            float* xd = lds + 1024 + (eo << 12) + (ep_s << 6) + (ep_g << 4);
            *(float4*)(xd + 0) = pfx0;  *(float4*)(xd + 4) = pfx1;
            *(float4*)(xd + 8) = pfx2;  *(float4*)(xd + 12) = pfx3;
            if (tid < 128) {
                float* gd = lds + (tid < 64 ? 9216 : 11264) + (eo << 10) + (gr_s << 4);
                *(float4*)(gd + 0) = pfg0;  *(float4*)(gd + 4) = pfg1;
                *(float4*)(gd + 8) = pfg2;  *(float4*)(gd + 12) = pfg3;
            }
        }

        asm volatile("s_waitcnt lgkmcnt(0)" ::: "memory");
        __builtin_amdgcn_s_barrier();
        asm volatile("" ::: "memory");

        float acc0 = 0, acc1 = 0, acc2 = 0, acc3 = 0;
        if (t > 0) {
            float hv[32];
#pragma unroll
            for (int q = 0; q < 8; q++) {
                int pg = (kg << 3) + (q ^ (kg & 7));
                float4 u = *(const float4*)&lds[(p << 9) + (pg << 2)];
                hv[q * 4 + 0] = u.x; hv[q * 4 + 1] = u.y;
                hv[q * 4 + 2] = u.z; hv[q * 4 + 3] = u.w;
            }
#pragma unroll
            for (int j = 0; j < 32; j++) {
                acc0 += hv[j] * wreg[0][j];
                acc1 += hv[j] * wreg[1][j];
                acc2 += hv[j] * wreg[2][j];
                acc3 += hv[j] * wreg[3][j];
            }
            acc0 += __shfl_xor(acc0, 1, 64); acc0 += __shfl_xor(acc0, 2, 64);
            acc0 += __shfl_xor(acc0, 4, 64); acc0 += __shfl_xor(acc0, 8, 64);
            acc1 += __shfl_xor(acc1, 1, 64); acc1 += __shfl_xor(acc1, 2, 64);
            acc1 += __shfl_xor(acc1, 4, 64); acc1 += __shfl_xor(acc1, 8, 64);
            acc2 += __shfl_xor(acc2, 1, 64); acc2 += __shfl_xor(acc2, 2, 64);
            acc2 += __shfl_xor(acc2, 4, 64); acc2 += __shfl_xor(acc2, 8, 64);
            acc3 += __shfl_xor(acc3, 1, 64); acc3 += __shfl_xor(acc3, 2, 64);
            acc3 += __shfl_xor(acc3, 4, 64); acc3 += __shfl_xor(acc3, 8, 64);
        }

        if (kg == 0) {
            const float* eb = lds + 1024 + (e << 12) + (es << 6);
            float xpv0 = eb[rq];
            float xpv1 = eb[16 + rq];
            float xpv2 = eb[32 + rq];
            float xpv3 = eb[48 + rq];
            float gv = lds[9216 + (e << 10) + (es << 4) + rq];
            float rv = lds[11264 + (e << 10) + (es << 4) + rq];
            float iv = sigf(acc0 + xpv0);
            float fv = sigf(acc1 + xpv1);
            float gt = tanhf_(acc2 + xpv2);
            float ov = sigf(acc3 + xpv3);
            c_reg = fv * c_reg + iv * gt;
            float h = ov * tanhf_(c_reg);
            unsigned long long pkt =
                ((unsigned long long)(unsigned)(t + 1) << 32) |
                (unsigned long long)__float_as_uint(h);
            __hip_atomic_store(h_safe + p * 4096 + (b << 9) + slot, pkt,
                               __ATOMIC_RELAXED, __HIP_MEMORY_SCOPE_AGENT);
            unsigned long long* fp = h_fast + p * 4096 + (b << 9) + slot;
            asm volatile("global_store_dwordx2 %0, %1, off sc0"
                         :: "v"(fp), "v"(pkt) : "memory");
            out[(long long)((b << 12) + t) * 512 + slot] = h * gv + rv;
            if (t == 4095) {
                out[16777216 + (b << 9) + slot] = h;            // hT
                out[16777216 + 4096 + (b << 9) + slot] = c_reg; // cT
            }
            if (i == CH - 1) c_buf[(b << 9) + slot] = c_reg;
        }
    }
    asm volatile("s_waitcnt vmcnt(0)" :: "v"(pa), "v"(pb) : "memory");
}

// ---------------------------------------------------------------------------
// launch: chunk T so the workspace fits ws_size.
// per-CH bytes: 106496*CH; persistent ~2.8MB
// ---------------------------------------------------------------------------
extern "C" void kernel_launch(void* const* d_in, const int* in_sizes, int n_in,
                              void* d_out, int out_size, void* d_ws, size_t ws_size,
                              hipStream_t stream) {
    const float* x     = (const float*)d_in[0];
    const float* W_ih  = (const float*)d_in[1];
    const float* W_hh  = (const float*)d_in[2];
    const float* b_ih  = (const float*)d_in[3];
    const float* b_hh  = (const float*)d_in[4];
    const float* gamma = (const float*)d_in[5];
    const float* beta  = (const float*)d_in[6];
    const float* W_lin = (const float*)d_in[7];
    const float* b_lin = (const float*)d_in[8];
    float* out = (float*)d_out;

    const size_t small_bytes = 16384ull * 8 + 4096ull * 4 +
                               (2048ull * 512 + 512ull * 512) * 2;
    int CH = 256;
    for (int cand = 4096; cand >= 256; cand >>= 1) {
        if ((size_t)106496 * cand + small_bytes <= ws_size) { CH = cand; break; }
    }
    int chsh = 31 - __builtin_clz(CH);

    float* ws      = (float*)d_ws;
    float* res_ch  = ws;
    float* gate_ch = res_ch + (size_t)8 * CH * 512;
    float* xp_ch   = gate_ch + (size_t)8 * CH * 512;
    unsigned short* res_bf = (unsigned short*)(xp_ch + (size_t)8 * CH * 2048);
    unsigned long long* h_fast = (unsigned long long*)(res_bf + (size_t)8 * CH * 512);
    unsigned long long* h_safe = h_fast + 8192;
    float* c_buf   = (float*)(h_safe + 8192);
    unsigned short* wbf_ih  = (unsigned short*)(c_buf + 4096);
    unsigned short* wbf_lin = wbf_ih + 2048 * 512;

    init_ws_kernel<<<64, 256, 0, stream>>>(h_fast);  // zeroes h_fast + h_safe
    cvt_bf16_kernel<<<1024, 256, 0, stream>>>(W_ih, wbf_ih, 2048 * 512 / 4);
    cvt_bf16_kernel<<<256, 256, 0, stream>>>(W_lin, wbf_lin, 512 * 512 / 4);

    int nchunks = 4096 / CH;
    for (int c = 0; c < nchunks; c++) {
        int t0 = c * CH;
        ln_kernel<<<8 * CH / 4, 256, 0, stream>>>(x, gamma, beta, res_ch, res_bf,
                                                  t0, chsh);
        gemm_mfma<0><<<dim3(8 * CH / 128, 16), 256, 0, stream>>>(
            res_bf, wbf_ih, b_ih, b_hh, xp_ch, 2048);
        gemm_mfma<1><<<dim3(8 * CH / 128, 4), 256, 0, stream>>>(
            res_bf, wbf_lin, b_lin, b_lin, gate_ch, 512);
        scan_kernel<<<256, 256, 0, stream>>>(W_hh, xp_ch, res_ch, gate_ch, out,
                                             h_fast, h_safe, c_buf, t0, chsh);
    }
}